// Round 11
// baseline (235.034 us; speedup 1.0000x reference)
//
#include <hip/hip_runtime.h>
#include <hip/hip_bf16.h>
#include <math.h>

// SIREN eigenfunction banks + small linear head.
// eigen: persistent-e kernel, merged T_IN/T_OUT. W fragments in regs.
// SWAPPED MFMA operands: D = W·x (row=o, col=t) -> act-stores are 4
// consecutive-o values => packed ds_write_b64 (bank-friendly), and the final
// 128->1 dot reduces in-register (x2 never stored). 3 barriers/iter.

typedef short  bf16x8 __attribute__((ext_vector_type(8)));
typedef float  f32x4  __attribute__((ext_vector_type(4)));
typedef unsigned short u16;
typedef u16    u16x8  __attribute__((ext_vector_type(8)));
typedef unsigned int u32;
typedef u32    u32x2  __attribute__((ext_vector_type(2)));
typedef u32    u32x4  __attribute__((ext_vector_type(4)));

constexpr int DD    = 128;
constexpr int E_TOT = 1024;
constexpr int T_INc = 512;
constexpr int T_OUTc= 256;
constexpr int BBc   = 32;
constexpr int CCc   = 64;
constexpr int NB1   = 17;
constexpr int EF_W  = NB1 * CCc;     // 1088
constexpr int LIN_I = EF_W + 4;      // 1092
constexpr int LIN_O = EF_W;          // 1088

__device__ __forceinline__ float b2f(u16 u) {
  unsigned v = ((unsigned)u) << 16;
  return __builtin_bit_cast(float, v);
}
// packed RNE pair via compiler intrinsic: low 16 bits = cvt(a), high = cvt(b)
__device__ __forceinline__ u32 pkrn(float a, float b) {
  __hip_bfloat162 h = __float22bfloat162_rn(float2{a, b});
  u32 r;
  __builtin_memcpy(&r, &h, 4);
  return r;
}

// XOR-swizzled element index into a row-major [rows][128] u16 LDS plane.
// byte = row*256 + ((col*2) ^ ((row&7)<<4)); preserves 8B blocks.
__device__ __forceinline__ int swz(int row, int col) {
  return row * DD + ((((col << 1) ^ ((row & 7) << 4)) >> 1));
}

// ---------------------------------------------------------------------------
// eigen_persist: grid = 2*E_TOT. Blocks [0,1024): T_IN; [1024,2048): T_OUT.
// 8 waves = (wt 0..1) x (wo 0..3); per 64-t iter a wave computes 32o x 32t.
// ---------------------------------------------------------------------------
__global__ __launch_bounds__(512, 2) void eigen_persist(
    const float* __restrict__ W0i, const float* __restrict__ b0i,
    const float* __restrict__ Whi, const float* __restrict__ bhi,
    const float* __restrict__ Wli, const float* __restrict__ bli,
    const float* __restrict__ w0ii, float* __restrict__ efni,
    const float* __restrict__ W0o, const float* __restrict__ b0o,
    const float* __restrict__ Who, const float* __restrict__ bho,
    const float* __restrict__ Wlo, const float* __restrict__ blo,
    const float* __restrict__ w0io, float* __restrict__ efno)
{
  __shared__ u16 xP[2][8192];          // x0 / x1 planes (64x128 bf16, swizzled)
  __shared__ float yPart[4 * 64];      // per-wo partial y[t]
  __shared__ float w0s[128], b0s[128];

  const bool isIn = (blockIdx.x < E_TOT);
  const int  e    = blockIdx.x & (E_TOT - 1);
  const int  NIT  = isIn ? (T_INc / 64) : (T_OUTc / 64);
  const float tstep = isIn ? (1.0f / (float)(T_INc - 1)) : (1.0f / (float)(T_OUTc - 1));
  const float* W0 = isIn ? W0i : W0o;
  const float* b0 = isIn ? b0i : b0o;
  const float* Wh = isIn ? Whi : Who;
  const float* bh = isIn ? bhi : bho;
  const float* Wl = isIn ? Wli : Wlo;
  const float* bl = isIn ? bli : blo;
  const float* w0i = isIn ? w0ii : w0io;
  float* efn = isIn ? efni : efno;

  const int tid  = threadIdx.x;
  const int lane = tid & 63;
  const int wv   = tid >> 6;      // wave 0..7
  const int wt   = wv >> 2;       // t-group: cols wt*32..+32
  const int wo   = wv & 3;        // o-group: rows wo*32..+32
  const int lm   = lane & 15;
  const int lg   = lane >> 4;

  // ---- stage small per-e vectors to LDS ----
  if (tid < 128)       w0s[tid]       = W0[(size_t)e * DD + tid];
  else if (tid < 256)  b0s[tid - 128] = b0[(size_t)e * DD + tid - 128];
  const float wi  = w0i[e];
  const float blv = bl[e];

  // ---- per-lane o-row constants: o = wo*32 + m*16 + lg*4 + r ----
  float4 bh1v[2], bh2v[2], wlv[2];
  #pragma unroll
  for (int m = 0; m < 2; ++m) {
    const int ob = wo * 32 + m * 16 + lg * 4;
    bh1v[m] = *(const float4*)(bh + (size_t)e * DD + ob);
    bh2v[m] = *(const float4*)(bh + ((size_t)E_TOT + e) * DD + ob);
    wlv[m]  = *(const float4*)(Wl + (size_t)e * DD + ob);
  }

  // ---- W fragments: lane(lm,lg) holds W[o = wo*32+m*16+lm][k = kk*32+lg*8..+7]
  bf16x8 wfrag[2][4][2];
  #pragma unroll
  for (int l = 0; l < 2; ++l) {
    const float* Wg = Wh + ((size_t)l * E_TOT + e) * (DD * DD);
    #pragma unroll
    for (int kk = 0; kk < 4; ++kk)
      #pragma unroll
      for (int m = 0; m < 2; ++m) {
        const float* p = Wg + (wo * 32 + m * 16 + lm) * DD + kk * 32 + lg * 8;
        const float4 a = *(const float4*)p;
        const float4 c = *(const float4*)(p + 4);
        u32x4 u;
        u[0] = pkrn(a.x, a.y);
        u[1] = pkrn(a.z, a.w);
        u[2] = pkrn(c.x, c.y);
        u[3] = pkrn(c.z, c.w);
        wfrag[l][kk][m] = __builtin_bit_cast(bf16x8, u);
      }
  }
  __syncthreads();   // w0s/b0s ready

  const int tl = tid >> 3;    // 0..63 (local t row, for L0)
  const int q  = tid & 7;     // d-chunk q*16..+15

  for (int it = 0; it < NIT; ++it) {
    u16* x0p = xP[0];
    u16* x1p = xP[1];

    // ---- layer 0 -> x0 plane ----
    {
      const float dom = (float)(it * 64 + tl) * tstep;
      #pragma unroll
      for (int c = 0; c < 2; ++c) {
        const int d = q * 16 + c * 8;
        const float4 wa = *(const float4*)&w0s[d];
        const float4 wb = *(const float4*)&w0s[d + 4];
        const float4 ba = *(const float4*)&b0s[d];
        const float4 bb = *(const float4*)&b0s[d + 4];
        u32x4 u;
        u[0] = pkrn(__sinf(wi * (wa.x * dom + ba.x)), __sinf(wi * (wa.y * dom + ba.y)));
        u[1] = pkrn(__sinf(wi * (wa.z * dom + ba.z)), __sinf(wi * (wa.w * dom + ba.w)));
        u[2] = pkrn(__sinf(wi * (wb.x * dom + bb.x)), __sinf(wi * (wb.y * dom + bb.y)));
        u[3] = pkrn(__sinf(wi * (wb.z * dom + bb.z)), __sinf(wi * (wb.w * dom + bb.w)));
        *(u16x8*)&x0p[swz(tl, d)] = __builtin_bit_cast(u16x8, u);
      }
    }
    __syncthreads();   // (1) x0 ready

    f32x4 acc[2][2];   // [m: o-group][n: t-group], D row=o, col=t

    // ---- hidden layer 1: acc = W1 . x0 ----
    #pragma unroll
    for (int m = 0; m < 2; ++m)
      #pragma unroll
      for (int n = 0; n < 2; ++n) acc[m][n] = (f32x4){0.f, 0.f, 0.f, 0.f};
    #pragma unroll
    for (int kk = 0; kk < 4; ++kk) {
      const int kb = kk * 32 + lg * 8;
      bf16x8 xf[2];
      #pragma unroll
      for (int n = 0; n < 2; ++n)
        xf[n] = *(const bf16x8*)&x0p[swz(wt * 32 + n * 16 + lm, kb)];
      #pragma unroll
      for (int m = 0; m < 2; ++m)
        #pragma unroll
        for (int n = 0; n < 2; ++n)
          acc[m][n] = __builtin_amdgcn_mfma_f32_16x16x32_bf16(wfrag[0][kk][m], xf[n], acc[m][n], 0, 0, 0);
    }
    // ---- act1 -> x1 plane (row=t col=o layout; 4 consecutive o per thread) ----
    #pragma unroll
    for (int m = 0; m < 2; ++m)
      #pragma unroll
      for (int n = 0; n < 2; ++n) {
        const int t  = wt * 32 + n * 16 + lm;
        const int ob = wo * 32 + m * 16 + lg * 4;
        u32x2 w2;
        w2[0] = pkrn(__sinf(acc[m][n][0] + bh1v[m].x), __sinf(acc[m][n][1] + bh1v[m].y));
        w2[1] = pkrn(__sinf(acc[m][n][2] + bh1v[m].z), __sinf(acc[m][n][3] + bh1v[m].w));
        *(u32x2*)&x1p[swz(t, ob)] = w2;
      }
    __syncthreads();   // (2) x1 ready (and all x0 reads done)

    // ---- hidden layer 2: acc = W2 . x1 ----
    #pragma unroll
    for (int m = 0; m < 2; ++m)
      #pragma unroll
      for (int n = 0; n < 2; ++n) acc[m][n] = (f32x4){0.f, 0.f, 0.f, 0.f};
    #pragma unroll
    for (int kk = 0; kk < 4; ++kk) {
      const int kb = kk * 32 + lg * 8;
      bf16x8 xf[2];
      #pragma unroll
      for (int n = 0; n < 2; ++n)
        xf[n] = *(const bf16x8*)&x1p[swz(wt * 32 + n * 16 + lm, kb)];
      #pragma unroll
      for (int m = 0; m < 2; ++m)
        #pragma unroll
        for (int n = 0; n < 2; ++n)
          acc[m][n] = __builtin_amdgcn_mfma_f32_16x16x32_bf16(wfrag[1][kk][m], xf[n], acc[m][n], 0, 0, 0);
    }

    // ---- act2 + final dot in-register: y[t] = sum_o Wl[o]*sin(acc+bh2) ----
    {
      float part0 = 0.f, part1 = 0.f;
      #pragma unroll
      for (int m = 0; m < 2; ++m) {
        const float* bp = (const float*)&bh2v[m];
        const float* wp = (const float*)&wlv[m];
        #pragma unroll
        for (int r = 0; r < 4; ++r) {
          part0 += wp[r] * __sinf(acc[m][0][r] + bp[r]);
          part1 += wp[r] * __sinf(acc[m][1][r] + bp[r]);
        }
      }
      // reduce over lg (lane bits 4,5)
      part0 += __shfl_xor(part0, 16);  part0 += __shfl_xor(part0, 32);
      part1 += __shfl_xor(part1, 16);  part1 += __shfl_xor(part1, 32);
      if (lg == 0) {
        yPart[wo * 64 + wt * 32 + lm]      = part0;
        yPart[wo * 64 + wt * 32 + 16 + lm] = part1;
      }
    }
    __syncthreads();   // (3) yPart ready (and all x1 reads done)

    if (tid < 64) {
      const float s = yPart[tid] + yPart[64 + tid] + yPart[128 + tid] + yPart[192 + tid];
      efn[(size_t)(it * 64 + tid) * EF_W + CCc + e] = s + blv;
    }
    // next-iter L0 writes x0 plane: all waves passed barrier (2)+(3) -> safe
  }
}

// ---------------------------------------------------------------------------
__global__ void normalize_kernel(float* __restrict__ efn)
{
  const int t = blockIdx.x;
  const int c = threadIdx.x;   // 64
  float* row = efn + (size_t)t * EF_W;
  float v[16];
  float s = 1.0f;
  #pragma unroll
  for (int n = 0; n < 16; ++n) {
    v[n] = row[CCc + n * CCc + c];
    s += v[n] * v[n];
  }
  const float inv = 1.0f / sqrtf(s);
  row[c] = inv;
  #pragma unroll
  for (int n = 0; n < 16; ++n)
    row[CCc + n * CCc + c] = v[n] * inv;
}

// coeffs: block (n, b), 512 thr = 64 c x 8 t-chunks, LDS reduce.
__global__ __launch_bounds__(512) void coeffs_kernel(
    const float* __restrict__ x_enc, const float* __restrict__ x_mark_enc,
    const float* __restrict__ efn_in, float* __restrict__ flat_in)
{
  const int n  = blockIdx.x;   // 17
  const int b  = blockIdx.y;   // 32
  const int c  = threadIdx.x & 63;
  const int ch = threadIdx.x >> 6;   // 0..7
  __shared__ float red[8][64];
  float acc = 0.0f;
  #pragma unroll 4
  for (int t = ch * 64; t < ch * 64 + 64; ++t)
    acc += x_enc[((size_t)b * T_INc + t) * CCc + c]
         * efn_in[(size_t)t * EF_W + n * CCc + c];
  red[ch][c] = acc;
  __syncthreads();
  if (ch == 0) {
    #pragma unroll
    for (int k = 1; k < 8; ++k) acc += red[k][c];
    flat_in[b * LIN_I + n * CCc + c] = acc;
    if (n == 0 && c < 4)
      flat_in[b * LIN_I + EF_W + c] =
          x_mark_enc[((size_t)b * T_INc + (T_INc - 1)) * 4 + c];
  }
}

// Wlin transpose (for coalesced GEMV)
__global__ __launch_bounds__(256) void transpose_lin(const float* __restrict__ W,
                                                     float* __restrict__ Wt)
{
  __shared__ float tile[32][33];
  const int j0 = blockIdx.x * 32;
  const int o0 = blockIdx.y * 32;
  const int tx = threadIdx.x & 31, ty = threadIdx.x >> 5;  // ty 0..7
  #pragma unroll
  for (int r = 0; r < 32; r += 8) {
    const int o = o0 + ty + r, j = j0 + tx;
    tile[ty + r][tx] = (o < LIN_O && j < LIN_I) ? W[(size_t)o * LIN_I + j] : 0.f;
  }
  __syncthreads();
  #pragma unroll
  for (int r = 0; r < 32; r += 8) {
    const int j = j0 + ty + r, o = o0 + tx;
    if (j < LIN_I && o < LIN_O) Wt[(size_t)j * LIN_O + o] = tile[tx][ty + r];
  }
}

// linear (transposed W): block (o-tile, b), 256 thr = 64 o x 4 j-chunks.
__global__ __launch_bounds__(256) void linear_t_kernel(
    const float* __restrict__ flat_in, const float* __restrict__ Wt,
    const float* __restrict__ blin, float* __restrict__ pred)
{
  const int og = blockIdx.x;   // 17
  const int b  = blockIdx.y;   // 32
  const int c  = threadIdx.x & 63;
  const int ch = threadIdx.x >> 6;
  const int o  = og * 64 + c;
  __shared__ float red[4][64];
  const float* xi = flat_in + b * LIN_I;
  float acc = 0.0f;
  #pragma unroll 4
  for (int j = ch * 273; j < ch * 273 + 273; ++j)
    acc += Wt[(size_t)j * LIN_O + o] * xi[j];
  red[ch][c] = acc;
  __syncthreads();
  if (ch == 0)
    pred[b * LIN_O + o] = acc + red[1][c] + red[2][c] + red[3][c] + blin[o];
}

// fallback row-major linear (if ws too small for Wt)
__global__ void linear_row_kernel(const float* __restrict__ flat_in,
                                  const float* __restrict__ Wlin,
                                  const float* __restrict__ blin,
                                  float* __restrict__ pred)
{
  const int o = blockIdx.x * 64 + threadIdx.x;
  const int b = blockIdx.y;
  const float* w  = Wlin + (size_t)o * LIN_I;
  const float* xi = flat_in + b * LIN_I;
  float acc = blin[o];
  for (int j = 0; j < LIN_I; ++j) acc += w[j] * xi[j];
  pred[b * LIN_O + o] = acc;
}

__global__ void recon_kernel(const float* __restrict__ pred,
                             const float* __restrict__ efn_out,
                             float* __restrict__ out)
{
  const int b = blockIdx.y;
  const int t = blockIdx.x * 4 + (threadIdx.x >> 6);
  const int c = threadIdx.x & 63;
  float acc = 0.0f;
  #pragma unroll
  for (int n = 0; n < NB1; ++n)
    acc += pred[b * LIN_O + n * CCc + c]
         * efn_out[(size_t)t * EF_W + n * CCc + c];
  out[((size_t)b * T_OUTc + t) * CCc + c] = acc;
}

// ---------------------------------------------------------------------------
extern "C" void kernel_launch(void* const* d_in, const int* in_sizes, int n_in,
                              void* d_out, int out_size, void* d_ws, size_t ws_size,
                              hipStream_t stream)
{
  const float* x_enc      = (const float*)d_in[0];
  const float* x_mark_enc = (const float*)d_in[1];
  const float* W0_in  = (const float*)d_in[4];
  const float* b0_in  = (const float*)d_in[5];
  const float* Wh_in  = (const float*)d_in[6];
  const float* bh_in  = (const float*)d_in[7];
  const float* Wl_in  = (const float*)d_in[8];
  const float* bl_in  = (const float*)d_in[9];
  const float* w0i_in = (const float*)d_in[10];
  const float* W0_out  = (const float*)d_in[11];
  const float* b0_out  = (const float*)d_in[12];
  const float* Wh_out  = (const float*)d_in[13];
  const float* bh_out  = (const float*)d_in[14];
  const float* Wl_out  = (const float*)d_in[15];
  const float* bl_out  = (const float*)d_in[16];
  const float* w0i_out = (const float*)d_in[17];
  const float* Wlin = (const float*)d_in[18];
  const float* blin = (const float*)d_in[19];

  float* ws      = (float*)d_ws;
  float* efn_in  = ws;                                   // 512*1088
  float* efn_out = efn_in + (size_t)T_INc * EF_W;        // 256*1088
  float* flat_in = efn_out + (size_t)T_OUTc * EF_W;      // 32*1092
  float* pred    = flat_in + (size_t)BBc * LIN_I;        // 32*1088
  float* Wt      = pred + (size_t)BBc * LIN_O;           // 1092*1088
  const size_t needWt = ((size_t)(Wt - ws) + (size_t)LIN_I * LIN_O) * sizeof(float);
  const bool useWt = (ws_size >= needWt);

  eigen_persist<<<dim3(2 * E_TOT), dim3(512), 0, stream>>>(
      W0_in, b0_in, Wh_in, bh_in, Wl_in, bl_in, w0i_in, efn_in,
      W0_out, b0_out, Wh_out, bh_out, Wl_out, bl_out, w0i_out, efn_out);

  normalize_kernel<<<dim3(T_INc),  dim3(64), 0, stream>>>(efn_in);
  normalize_kernel<<<dim3(T_OUTc), dim3(64), 0, stream>>>(efn_out);

  coeffs_kernel<<<dim3(NB1, BBc), dim3(512), 0, stream>>>(x_enc, x_mark_enc, efn_in, flat_in);

  if (useWt) {
    transpose_lin<<<dim3((LIN_I + 31) / 32, (LIN_O + 31) / 32), dim3(256), 0, stream>>>(Wlin, Wt);
    linear_t_kernel<<<dim3(NB1, BBc), dim3(256), 0, stream>>>(flat_in, Wt, blin, pred);
  } else {
    linear_row_kernel<<<dim3(NB1, BBc), dim3(64), 0, stream>>>(flat_in, Wlin, blin, pred);
  }

  recon_kernel<<<dim3(T_OUTc / 4, BBc), dim3(256), 0, stream>>>(pred, efn_out, (float*)d_out);
}